// Round 14
// baseline (517.692 us; speedup 1.0000x reference)
//
#include <hip/hip_runtime.h>
#include <cstdint>

typedef unsigned short u16;
typedef __attribute__((ext_vector_type(8))) __bf16 bf16x8;
typedef __attribute__((ext_vector_type(4))) float f32x4;

__device__ __forceinline__ u16 f2bf(float f) {
  unsigned int u = __builtin_bit_cast(unsigned int, f);
  unsigned int r = (u + 0x7fffu + ((u >> 16) & 1u)) >> 16;
  return (u16)r;
}
__device__ __forceinline__ float bf2f(u16 u) {
  return __builtin_bit_cast(float, (unsigned int)u << 16);
}

// async global->LDS, 16B per lane. LDS dest must be linear in lane (wave base + lane*16).
__device__ __forceinline__ void gload16(const u16* g, u16* l) {
  __builtin_amdgcn_global_load_lds((const __attribute__((address_space(1))) void*)g,
                                   (__attribute__((address_space(3))) void*)l, 16, 0, 0);
}

// XOR-swizzle helpers for flash kernel LDS.
__device__ __forceinline__ int swz64i(int row, int col) {   // 64 u16 cols per row
  return row * 64 + (((col & 0x38) ^ ((row & 7) << 3)) | (col & 7));
}
__device__ __forceinline__ int swz128i(int row, int col) {  // 128 u16 cols per row
  return row * 128 + (((col & 0x78) ^ ((row & 7) << 3)) | (col & 7));
}

// ---------------- fp32 -> bf16 conversion ----------------
__global__ __launch_bounds__(256) void cvt_bf16_kernel(const float* __restrict__ in,
                                                       u16* __restrict__ out, long n4) {
  long i = (long)blockIdx.x * 256 + threadIdx.x;
  long stride = (long)gridDim.x * 256;
  const float4* in4 = (const float4*)in;
  uint2* out2 = (uint2*)out;
  for (long k = i; k < n4; k += stride) {
    float4 v = in4[k];
    uint2 o;
    o.x = (unsigned int)f2bf(v.x) | ((unsigned int)f2bf(v.y) << 16);
    o.y = (unsigned int)f2bf(v.z) | ((unsigned int)f2bf(v.w) << 16);
    out2[k] = o;
  }
}

// ---------------- 256x192 2-phase m-split bf16 GEMM (QKV; bf16 out) [R10 proven] ----
__global__ __launch_bounds__(512, 2) void gemm192(const u16* __restrict__ A,
                                                  const u16* __restrict__ B,
                                                  u16* __restrict__ C,
                                                  int Ndim, int Kdim) {
  extern __shared__ __align__(16) u16 lds[];   // A: 3*16384 u16 @0, B: 2*12288 u16 @49152
  const int tid = threadIdx.x;
  const int lane = tid & 63, wave = tid >> 6;
  const int wr = wave >> 2, wc = wave & 3;
  const int l15 = lane & 15, l4 = lane >> 4;
  const int gx = gridDim.x;
  int lin = blockIdx.y * gx + blockIdx.x;
  const int xcd = lin & 7, ii = lin >> 3;
  const int bx = xcd * (gx >> 3) + (ii >> 3), by = ii & 7;
  const long arow = (long)by * 256, brow = (long)bx * 192;
  const int NT = Kdim >> 6;

  const int rowt = tid >> 3;
  const int koff = ((tid & 7) ^ (rowt & 7)) * 8;
  const u16* gA[4];
  const u16* gB[3];
  #pragma unroll
  for (int r = 0; r < 4; ++r) gA[r] = A + (size_t)(arow + rowt + r * 64) * Kdim + koff;
  #pragma unroll
  for (int r = 0; r < 3; ++r) gB[r] = B + (size_t)(brow + rowt + r * 64) * Kdim + koff;
  u16* const ldsB = lds + 49152;

  auto STA = [&](int u) {
    u16* d = lds + (u % 3) * 16384 + tid * 8;
    #pragma unroll
    for (int r = 0; r < 4; ++r) gload16(gA[r] + (size_t)u * 64, d + r * 4096);
  };
  auto STB = [&](int u) {
    u16* d = ldsB + (u & 1) * 12288 + tid * 8;
    #pragma unroll
    for (int r = 0; r < 3; ++r) gload16(gB[r] + (size_t)u * 64, d + r * 4096);
  };

  bf16x8 af[4][2], bfr[3][2];
  f32x4 acc[8][3] = {};
  int cks[2];
  #pragma unroll
  for (int kc = 0; kc < 2; ++kc) cks[kc] = (((kc * 4 + l4) ^ (l15 & 7)) * 8);

  auto LDA4 = [&](int u, int mh) {
    const u16* base = lds + (u % 3) * 16384 + (wr * 128 + mh * 64 + l15) * 64;
    #pragma unroll
    for (int m = 0; m < 4; ++m)
      #pragma unroll
      for (int kc = 0; kc < 2; ++kc)
        af[m][kc] = *(const bf16x8*)(base + m * 1024 + cks[kc]);
  };
  auto LDBall = [&](int u) {
    const u16* base = ldsB + (u & 1) * 12288 + (wc * 48 + l15) * 64;
    #pragma unroll
    for (int nh = 0; nh < 3; ++nh)
      #pragma unroll
      for (int kc = 0; kc < 2; ++kc)
        bfr[nh][kc] = *(const bf16x8*)(base + nh * 1024 + cks[kc]);
  };
  auto MM24 = [&](int mh) {
    #pragma unroll
    for (int kc = 0; kc < 2; ++kc)
      #pragma unroll
      for (int m = 0; m < 4; ++m)
        #pragma unroll
        for (int nh = 0; nh < 3; ++nh)
          acc[mh * 4 + m][nh] = __builtin_amdgcn_mfma_f32_16x16x32_bf16(
              af[m][kc], bfr[nh][kc], acc[mh * 4 + m][nh], 0, 0, 0);
  };

#define PH_BEGIN() do { __builtin_amdgcn_s_barrier();                         \
    asm volatile("s_waitcnt lgkmcnt(0)" ::: "memory");                        \
    __builtin_amdgcn_sched_barrier(0);                                        \
    __builtin_amdgcn_s_setprio(1); } while (0)
#define PH_END() do { __builtin_amdgcn_s_setprio(0);                          \
    __builtin_amdgcn_s_barrier(); } while (0)

  STA(0); STB(0); STA(1);
  asm volatile("s_waitcnt vmcnt(4)" ::: "memory");
  __builtin_amdgcn_s_barrier();

  for (int u = 0; u < NT; ++u) {
    LDA4(u, 0); LDBall(u);
    if (u + 1 < NT) STB(u + 1);
    PH_BEGIN(); MM24(0); PH_END();
    LDA4(u, 1);
    if (u + 2 < NT) STA(u + 2);
    PH_BEGIN(); MM24(1);
    __builtin_amdgcn_s_setprio(0);
    if (u + 2 < NT) { asm volatile("s_waitcnt vmcnt(4)" ::: "memory"); }
    else            { asm volatile("s_waitcnt vmcnt(0)" ::: "memory"); }
    __builtin_amdgcn_s_barrier();
  }
#undef PH_BEGIN
#undef PH_END

  #pragma unroll
  for (int m = 0; m < 8; ++m)
    #pragma unroll
    for (int nh = 0; nh < 3; ++nh)
      #pragma unroll
      for (int j = 0; j < 4; ++j) {
        long r = arow + wr * 128 + m * 16 + l4 * 4 + j;
        long c = brow + wc * 48 + nh * 16 + l15;
        C[r * Ndim + c] = f2bf(acc[m][nh][j]);
      }
}

// ---------------- 256x128 2-phase bf16 GEMM (out-proj; fp32 out) [R10 proven] -----
__global__ __launch_bounds__(512, 2) void gemm256(const u16* __restrict__ A,
                                                  const u16* __restrict__ B,
                                                  float* __restrict__ C,
                                                  int Ndim, int Kdim) {
  extern __shared__ __align__(16) u16 lds[];
  const int tid = threadIdx.x;
  const int lane = tid & 63, wave = tid >> 6;
  const int wr = wave >> 2, wc = wave & 3;
  const int l15 = lane & 15, l4 = lane >> 4;
  const int gx = gridDim.x;
  int lin = blockIdx.y * gx + blockIdx.x;
  const int xcd = lin & 7, ii = lin >> 3;
  const int bx = xcd * (gx >> 3) + (ii >> 3), by = ii & 7;
  const long arow = (long)by * 256, brow = (long)bx * 128;
  const int NT = Kdim >> 6;

  const int rowt = tid >> 3;
  const int koff = ((tid & 7) ^ (rowt & 7)) * 8;
  const u16* gA[4];
  const u16* gB[2];
  #pragma unroll
  for (int r = 0; r < 4; ++r) gA[r] = A + (size_t)(arow + rowt + r * 64) * Kdim + koff;
  #pragma unroll
  for (int r = 0; r < 2; ++r) gB[r] = B + (size_t)(brow + rowt + r * 64) * Kdim + koff;

  auto STA = [&](int u) {
    u16* d = lds + (u % 3) * 16384 + tid * 8;
    #pragma unroll
    for (int r = 0; r < 4; ++r) gload16(gA[r] + (size_t)u * 64, d + r * 4096);
  };
  auto STB = [&](int u) {
    u16* d = lds + 49152 + (u & 1) * 8192 + tid * 8;
    #pragma unroll
    for (int r = 0; r < 2; ++r) gload16(gB[r] + (size_t)u * 64, d + r * 4096);
  };

  bf16x8 af[4][2], bfr[2][2];
  f32x4 acc[8][2] = {};
  int cks[2];
  #pragma unroll
  for (int kc = 0; kc < 2; ++kc) cks[kc] = (((kc * 4 + l4) ^ (l15 & 7)) * 8);

  auto LDA = [&](int u, int mh) {
    const u16* base = lds + (u % 3) * 16384 + (wr * 128 + mh * 64 + l15) * 64;
    #pragma unroll
    for (int m = 0; m < 4; ++m)
      #pragma unroll
      for (int kc = 0; kc < 2; ++kc)
        af[m][kc] = *(const bf16x8*)(base + m * 1024 + cks[kc]);
  };
  auto LDB = [&](int u) {
    const u16* base = lds + 49152 + (u & 1) * 8192 + (wc * 32 + l15) * 64;
    #pragma unroll
    for (int n = 0; n < 2; ++n)
      #pragma unroll
      for (int kc = 0; kc < 2; ++kc)
        bfr[n][kc] = *(const bf16x8*)(base + n * 1024 + cks[kc]);
  };
  auto MM = [&](int mh) {
    #pragma unroll
    for (int kc = 0; kc < 2; ++kc)
      #pragma unroll
      for (int m = 0; m < 4; ++m)
        #pragma unroll
        for (int n = 0; n < 2; ++n)
          acc[mh * 4 + m][n] =
            __builtin_amdgcn_mfma_f32_16x16x32_bf16(af[m][kc], bfr[n][kc],
                                                    acc[mh * 4 + m][n], 0, 0, 0);
  };

#define PH_BEGIN() do { __builtin_amdgcn_s_barrier();                         \
    asm volatile("s_waitcnt lgkmcnt(0)" ::: "memory");                        \
    __builtin_amdgcn_sched_barrier(0);                                        \
    __builtin_amdgcn_s_setprio(1); } while (0)

  STA(0); STB(0); STA(1); STB(1);
  asm volatile("s_waitcnt vmcnt(6)" ::: "memory");
  __builtin_amdgcn_s_barrier();

  for (int u = 0; u < NT; ++u) {
    LDA(u, 0); LDB(u);
    if (u + 2 < NT) STA(u + 2);
    PH_BEGIN(); MM(0);
    __builtin_amdgcn_s_setprio(0);
    __builtin_amdgcn_s_barrier();
    LDA(u, 1);
    if (u + 2 < NT) STB(u + 2);
    PH_BEGIN(); MM(1);
    __builtin_amdgcn_s_setprio(0);
    if (u + 2 < NT) { asm volatile("s_waitcnt vmcnt(6)" ::: "memory"); }
    else if (u + 1 < NT) { asm volatile("s_waitcnt vmcnt(0)" ::: "memory"); }
    __builtin_amdgcn_s_barrier();
  }
#undef PH_BEGIN

  #pragma unroll
  for (int M = 0; M < 8; ++M)
    #pragma unroll
    for (int n = 0; n < 2; ++n)
      #pragma unroll
      for (int j = 0; j < 4; ++j) {
        long r = arow + wr * 128 + M * 16 + l4 * 4 + j;
        long c = brow + wc * 32 + n * 16 + l15;
        C[r * Ndim + c] = acc[M][n][j];
      }
}

// ---------------- fused per-head LayerNorm + RoPE, bf16 in/out (batched 4 rows/wave) ----
__global__ __launch_bounds__(256) void ln_rope_kernel(
    const u16* __restrict__ qkv, const int* __restrict__ pos,
    const float* __restrict__ qw, const float* __restrict__ qb2,
    const float* __restrict__ kw, const float* __restrict__ kb2,
    u16* __restrict__ qo, u16* __restrict__ ko, u16* __restrict__ vo, int T) {
  const int hh = blockIdx.x;
  const int t0 = blockIdx.y * 16 + (threadIdx.x >> 6) * 4;
  const int lane = threadIdx.x & 63;
  if (hh >= 64) {   // v: pure bit-copy [t][hh*128+d] -> [h][t][d]  (scalar, R11-proven)
    #pragma unroll
    for (int i = 0; i < 4; ++i) {
      int t = t0 + i;
      const u16* src = qkv + (size_t)t * 12288 + hh * 128;
      u16* dst = vo + ((size_t)(hh - 64) * T + t) * 128;
      dst[lane] = src[lane];
      dst[lane + 64] = src[lane + 64];
    }
    return;
  }
  bool isq = hh < 32;
  int hl = isq ? hh : hh - 32;
  const float* wp = (isq ? qw : kw) + hl * 128;
  const float* bp = (isq ? qb2 : kb2) + hl * 128;
  float w1 = wp[lane], w2 = wp[lane + 64];
  float b1 = bp[lane], b2 = bp[lane + 64];
  float invf = exp2f((float)lane * (-13.287712379549449f / 64.0f));
  u16* obase = (isq ? qo : ko) + (size_t)hl * T * 128;
  const float sc = isq ? 0.08838834764831845f : 1.0f;   // 1/sqrt(128) folded into q
  #pragma unroll
  for (int i = 0; i < 4; ++i) {
    int t = t0 + i;
    const u16* src = qkv + (size_t)t * 12288 + hh * 128;
    float x1 = bf2f(src[lane]), x2 = bf2f(src[lane + 64]);
    float s = x1 + x2;
    #pragma unroll
    for (int off = 32; off; off >>= 1) s += __shfl_xor(s, off);
    float mu = s * (1.0f / 128.0f);
    float d1 = x1 - mu, d2 = x2 - mu;
    float vs = d1 * d1 + d2 * d2;
    #pragma unroll
    for (int off = 32; off; off >>= 1) vs += __shfl_xor(vs, off);
    float rstd = rsqrtf(vs * (1.0f / 128.0f) + 1e-5f);
    float y1 = d1 * rstd * w1 + b1;
    float y2 = d2 * rstd * w2 + b2;
    float fr = (float)pos[t] * invf;
    float sn, cs;
    __sincosf(fr, &sn, &cs);
    float o1 = (y1 * cs - y2 * sn) * sc;
    float o2 = (y2 * cs + y1 * sn) * sc;
    u16* dst = obase + (size_t)t * 128;
    dst[lane] = f2bf(o1); dst[lane + 64] = f2bf(o2);
  }
}

// ---------------- flash attention (causal): 512 blocks, even/odd complementary pairing ----
// p = bid>>1, h = p&31, pi = bid>>6; qt = (bid&1) ? pi : nqt-1-pi.
// Consecutive bids (2p, 2p+1) = LONG + SHORT of the same pair -> if the dispatcher hands
// consecutive bids to one CU (R9/R13 evidence), each CU's two co-resident blocks sum to a
// uniform 36 KV-tiles. 2 blocks/CU (48KB LDS, VGPR 76) -> 16 waves/CU for overlap.
__global__ __launch_bounds__(512, 2) void flash_kernel(
    const u16* __restrict__ qb, const u16* __restrict__ kb,
    const u16* __restrict__ vb, u16* __restrict__ attn, int T) {
  extern __shared__ __align__(16) u16 flds[];
  u16* const Ks = flds;            // 64x128 swizzled (8192 u16)
  u16* const Vt = flds + 8192;     // 128x64 transposed swizzled (8192 u16)
  u16* const Ps = flds + 16384;    // 8 x (16x64) per-wave (8192 u16)
  const int tid = threadIdx.x;
  const int lane = tid & 63, wave = tid >> 6;
  const int l15 = lane & 15, l4 = lane >> 4;
  const int bid = blockIdx.x;
  const int nqt = T >> 7;
  const int h = (bid >> 1) & 31;
  const int pi = bid >> 6;
  const int qt = (bid & 1) ? pi : (nqt - 1 - pi);
  const int qbase = qt * 128;
  const u16* Q  = qb + (size_t)h * T * 128;
  const u16* Kp = kb + (size_t)h * T * 128;
  const u16* Vp = vb + (size_t)h * T * 128;
  const int rK = tid >> 4, d8k = (tid & 15) * 8;
  const int rv = tid & 63, dv0 = (tid >> 6) * 8;
  u16* const Pw = Ps + wave * 1024;

  const int r0g = qbase + wave * 16;   // this wave's 16 q-rows
  bf16x8 qf[4];
  #pragma unroll
  for (int kc = 0; kc < 4; ++kc)
    qf[kc] = *(const bf16x8*)&Q[(size_t)(r0g + l15) * 128 + kc * 32 + l4 * 8];

  float m_st[4], l_st[4];
  f32x4 o[8] = {};
  #pragma unroll
  for (int j = 0; j < 4; ++j) { m_st[j] = -1e30f; l_st[j] = 0.0f; }

  const int ntile = 2 * qt + 2;
  uint4 kr[2], vr[2];
  #pragma unroll
  for (int c = 0; c < 2; ++c) {
    kr[c] = *(const uint4*)&Kp[(size_t)(rK + 32 * c) * 128 + d8k];
    vr[c] = *(const uint4*)&Vp[(size_t)rv * 128 + dv0 + 64 * c];
  }
  for (int kt = 0; kt < ntile; ++kt) {
    const int kbase = kt * 64;
    #pragma unroll
    for (int c = 0; c < 2; ++c) {
      *(uint4*)&Ks[swz128i(rK + 32 * c, d8k)] = kr[c];
      const u16* pv = (const u16*)&vr[c];
      #pragma unroll
      for (int j = 0; j < 8; ++j) Vt[swz64i(dv0 + 64 * c + j, rv)] = pv[j];
    }
    __syncthreads();
    if (kt + 1 < ntile) {
      const int nb = kbase + 64;
      #pragma unroll
      for (int c = 0; c < 2; ++c) {
        kr[c] = *(const uint4*)&Kp[(size_t)(nb + rK + 32 * c) * 128 + d8k];
        vr[c] = *(const uint4*)&Vp[(size_t)(nb + rv) * 128 + dv0 + 64 * c];
      }
    }
    if (kbase <= r0g + 15) {
      f32x4 s[4] = {};
      __builtin_amdgcn_s_setprio(1);
      #pragma unroll
      for (int kc = 0; kc < 4; ++kc)
        #pragma unroll
        for (int nj = 0; nj < 4; ++nj) {
          bf16x8 kf = *(const bf16x8*)&Ks[swz128i(nj * 16 + l15, kc * 32 + l4 * 8)];
          s[nj] = __builtin_amdgcn_mfma_f32_16x16x32_bf16(qf[kc], kf, s[nj], 0, 0, 0);
        }
      __builtin_amdgcn_s_setprio(0);
      if (kbase + 63 > r0g) {
        #pragma unroll
        for (int nj = 0; nj < 4; ++nj)
          #pragma unroll
          for (int j = 0; j < 4; ++j) {
            int r = r0g + l4 * 4 + j;
            int cc = kbase + nj * 16 + l15;
            if (cc > r) s[nj][j] = -1e30f;
          }
      }
      float vmax[4];
      float dmax = -1e30f;
      #pragma unroll
      for (int j = 0; j < 4; ++j) {
        float v = fmaxf(fmaxf(s[0][j], s[1][j]), fmaxf(s[2][j], s[3][j]));
        #pragma unroll
        for (int off = 1; off < 16; off <<= 1) v = fmaxf(v, __shfl_xor(v, off));
        vmax[j] = v;
        dmax = fmaxf(dmax, v - m_st[j]);
      }
      if (!__all(dmax <= 8.0f)) {
        #pragma unroll
        for (int j = 0; j < 4; ++j) {
          float mn = fmaxf(m_st[j], vmax[j]);
          float scl = __expf(m_st[j] - mn);
          m_st[j] = mn;
          l_st[j] *= scl;
          #pragma unroll
          for (int nf = 0; nf < 8; ++nf) o[nf][j] *= scl;
        }
      }
      float sum[4] = {0.f, 0.f, 0.f, 0.f};
      #pragma unroll
      for (int nj = 0; nj < 4; ++nj)
        #pragma unroll
        for (int j = 0; j < 4; ++j) {
          float p = __expf(s[nj][j] - m_st[j]);
          s[nj][j] = p;
          sum[j] += p;
        }
      #pragma unroll
      for (int j = 0; j < 4; ++j) {
        #pragma unroll
        for (int off = 1; off < 16; off <<= 1) sum[j] += __shfl_xor(sum[j], off);
        l_st[j] += sum[j];
      }
      #pragma unroll
      for (int nj = 0; nj < 4; ++nj)
        #pragma unroll
        for (int j = 0; j < 4; ++j)
          Pw[swz64i(l4 * 4 + j, nj * 16 + l15)] = f2bf(s[nj][j]);
      asm volatile("s_waitcnt lgkmcnt(0)" ::: "memory");
      __builtin_amdgcn_sched_barrier(0);
      __builtin_amdgcn_s_setprio(1);
      #pragma unroll
      for (int kc = 0; kc < 2; ++kc) {
        bf16x8 pf = *(const bf16x8*)&Pw[swz64i(l15, kc * 32 + l4 * 8)];
        #pragma unroll
        for (int nf = 0; nf < 8; ++nf) {
          bf16x8 vf = *(const bf16x8*)&Vt[swz64i(nf * 16 + l15, kc * 32 + l4 * 8)];
          o[nf] = __builtin_amdgcn_mfma_f32_16x16x32_bf16(pf, vf, o[nf], 0, 0, 0);
        }
      }
      __builtin_amdgcn_s_setprio(0);
    }
    __syncthreads();
  }
  float rl[4];
  #pragma unroll
  for (int j = 0; j < 4; ++j) rl[j] = 1.0f / l_st[j];
  #pragma unroll
  for (int nf = 0; nf < 8; ++nf)
    #pragma unroll
    for (int j = 0; j < 4; ++j) {
      int r = r0g + l4 * 4 + j;
      int cc = h * 128 + nf * 16 + l15;
      attn[(size_t)r * 4096 + cc] = f2bf(o[nf][j] * rl[j]);
    }
}

// ---------------- launch ----------------
extern "C" void kernel_launch(void* const* d_in, const int* in_sizes, int n_in,
                              void* d_out, int out_size, void* d_ws, size_t ws_size,
                              hipStream_t stream) {
  const int* positions = (const int*)d_in[0];
  const float* hidden  = (const float*)d_in[1];
  const float* w_qkv   = (const float*)d_in[2];
  const float* w_o     = (const float*)d_in[3];
  const float* qnw     = (const float*)d_in[4];
  const float* qnb     = (const float*)d_in[5];
  const float* knw     = (const float*)d_in[6];
  const float* knb     = (const float*)d_in[7];
  float* out = (float*)d_out;

  const int T = in_sizes[0];           // 2048
  const int HID = 4096, NQKV = 12288, H = 32;

  char* ws = (char*)d_ws;
  u16* hid_bf  = (u16*)ws;
  u16* wreg    = (u16*)(ws + (size_t)T * HID * 2);
  u16* qkv_bf  = (u16*)(ws + (size_t)T * HID * 2 + (size_t)NQKV * HID * 2);

  u16* q_bf  = wreg;                                 // [H][T][128]
  u16* k_bf  = q_bf + (size_t)H * T * 128;
  u16* v_bf  = k_bf + (size_t)H * T * 128;
  u16* at_bf = v_bf + (size_t)H * T * 128;           // [T][H*128]
  u16* wo_bf = at_bf + (size_t)T * 4096;             // [4096][4096]

  hipFuncSetAttribute(reinterpret_cast<const void*>(&gemm192),
                      hipFuncAttributeMaxDynamicSharedMemorySize, 147456);
  hipFuncSetAttribute(reinterpret_cast<const void*>(&gemm256),
                      hipFuncAttributeMaxDynamicSharedMemorySize, 131072);
  hipFuncSetAttribute(reinterpret_cast<const void*>(&flash_kernel),
                      hipFuncAttributeMaxDynamicSharedMemorySize, 49152);

  cvt_bf16_kernel<<<2048, 256, 0, stream>>>(hidden, hid_bf, (long)T * HID / 4);
  cvt_bf16_kernel<<<4096, 256, 0, stream>>>(w_qkv, wreg, (long)NQKV * HID / 4);
  gemm192<<<dim3(NQKV / 192, T / 256), 512, 147456, stream>>>(hid_bf, wreg, qkv_bf, NQKV, HID);
  ln_rope_kernel<<<dim3(96, T / 16), 256, 0, stream>>>(qkv_bf, positions, qnw, qnb, knw, knb,
                                                       q_bf, k_bf, v_bf, T);
  cvt_bf16_kernel<<<2048, 256, 0, stream>>>(w_o, wo_bf, (long)HID * HID / 4);
  flash_kernel<<<512, 512, 49152, stream>>>(q_bf, k_bf, v_bf, at_bf, T);
  gemm256<<<dim3(HID / 128, T / 256), 512, 131072, stream>>>(at_bf, wo_bf, out, HID, HID);
}

// Round 15
// 498.247 us; speedup vs baseline: 1.0390x; 1.0390x over previous
//
#include <hip/hip_runtime.h>
#include <cstdint>

typedef unsigned short u16;
typedef __attribute__((ext_vector_type(8))) __bf16 bf16x8;
typedef __attribute__((ext_vector_type(4))) float f32x4;

__device__ __forceinline__ u16 f2bf(float f) {
  unsigned int u = __builtin_bit_cast(unsigned int, f);
  unsigned int r = (u + 0x7fffu + ((u >> 16) & 1u)) >> 16;
  return (u16)r;
}
__device__ __forceinline__ float bf2f(u16 u) {
  return __builtin_bit_cast(float, (unsigned int)u << 16);
}

// async global->LDS, 16B per lane. LDS dest must be linear in lane (wave base + lane*16).
__device__ __forceinline__ void gload16(const u16* g, u16* l) {
  __builtin_amdgcn_global_load_lds((const __attribute__((address_space(1))) void*)g,
                                   (__attribute__((address_space(3))) void*)l, 16, 0, 0);
}

// XOR-swizzle helpers for flash kernel LDS.
__device__ __forceinline__ int swz64i(int row, int col) {   // 64 u16 cols per row
  return row * 64 + (((col & 0x38) ^ ((row & 7) << 3)) | (col & 7));
}
__device__ __forceinline__ int swz128i(int row, int col) {  // 128 u16 cols per row
  return row * 128 + (((col & 0x78) ^ ((row & 7) << 3)) | (col & 7));
}

// ---------------- fp32 -> bf16 conversion ----------------
__global__ __launch_bounds__(256) void cvt_bf16_kernel(const float* __restrict__ in,
                                                       u16* __restrict__ out, long n4) {
  long i = (long)blockIdx.x * 256 + threadIdx.x;
  long stride = (long)gridDim.x * 256;
  const float4* in4 = (const float4*)in;
  uint2* out2 = (uint2*)out;
  for (long k = i; k < n4; k += stride) {
    float4 v = in4[k];
    uint2 o;
    o.x = (unsigned int)f2bf(v.x) | ((unsigned int)f2bf(v.y) << 16);
    o.y = (unsigned int)f2bf(v.z) | ((unsigned int)f2bf(v.w) << 16);
    out2[k] = o;
  }
}

// ---------------- 256x192 2-phase m-split bf16 GEMM (QKV; bf16 out) [R10 proven] ----
__global__ __launch_bounds__(512, 2) void gemm192(const u16* __restrict__ A,
                                                  const u16* __restrict__ B,
                                                  u16* __restrict__ C,
                                                  int Ndim, int Kdim) {
  extern __shared__ __align__(16) u16 lds[];   // A: 3*16384 u16 @0, B: 2*12288 u16 @49152
  const int tid = threadIdx.x;
  const int lane = tid & 63, wave = tid >> 6;
  const int wr = wave >> 2, wc = wave & 3;
  const int l15 = lane & 15, l4 = lane >> 4;
  const int gx = gridDim.x;
  int lin = blockIdx.y * gx + blockIdx.x;
  const int xcd = lin & 7, ii = lin >> 3;
  const int bx = xcd * (gx >> 3) + (ii >> 3), by = ii & 7;
  const long arow = (long)by * 256, brow = (long)bx * 192;
  const int NT = Kdim >> 6;

  const int rowt = tid >> 3;
  const int koff = ((tid & 7) ^ (rowt & 7)) * 8;
  const u16* gA[4];
  const u16* gB[3];
  #pragma unroll
  for (int r = 0; r < 4; ++r) gA[r] = A + (size_t)(arow + rowt + r * 64) * Kdim + koff;
  #pragma unroll
  for (int r = 0; r < 3; ++r) gB[r] = B + (size_t)(brow + rowt + r * 64) * Kdim + koff;
  u16* const ldsB = lds + 49152;

  auto STA = [&](int u) {
    u16* d = lds + (u % 3) * 16384 + tid * 8;
    #pragma unroll
    for (int r = 0; r < 4; ++r) gload16(gA[r] + (size_t)u * 64, d + r * 4096);
  };
  auto STB = [&](int u) {
    u16* d = ldsB + (u & 1) * 12288 + tid * 8;
    #pragma unroll
    for (int r = 0; r < 3; ++r) gload16(gB[r] + (size_t)u * 64, d + r * 4096);
  };

  bf16x8 af[4][2], bfr[3][2];
  f32x4 acc[8][3] = {};
  int cks[2];
  #pragma unroll
  for (int kc = 0; kc < 2; ++kc) cks[kc] = (((kc * 4 + l4) ^ (l15 & 7)) * 8);

  auto LDA4 = [&](int u, int mh) {
    const u16* base = lds + (u % 3) * 16384 + (wr * 128 + mh * 64 + l15) * 64;
    #pragma unroll
    for (int m = 0; m < 4; ++m)
      #pragma unroll
      for (int kc = 0; kc < 2; ++kc)
        af[m][kc] = *(const bf16x8*)(base + m * 1024 + cks[kc]);
  };
  auto LDBall = [&](int u) {
    const u16* base = ldsB + (u & 1) * 12288 + (wc * 48 + l15) * 64;
    #pragma unroll
    for (int nh = 0; nh < 3; ++nh)
      #pragma unroll
      for (int kc = 0; kc < 2; ++kc)
        bfr[nh][kc] = *(const bf16x8*)(base + nh * 1024 + cks[kc]);
  };
  auto MM24 = [&](int mh) {
    #pragma unroll
    for (int kc = 0; kc < 2; ++kc)
      #pragma unroll
      for (int m = 0; m < 4; ++m)
        #pragma unroll
        for (int nh = 0; nh < 3; ++nh)
          acc[mh * 4 + m][nh] = __builtin_amdgcn_mfma_f32_16x16x32_bf16(
              af[m][kc], bfr[nh][kc], acc[mh * 4 + m][nh], 0, 0, 0);
  };

#define PH_BEGIN() do { __builtin_amdgcn_s_barrier();                         \
    asm volatile("s_waitcnt lgkmcnt(0)" ::: "memory");                        \
    __builtin_amdgcn_sched_barrier(0);                                        \
    __builtin_amdgcn_s_setprio(1); } while (0)
#define PH_END() do { __builtin_amdgcn_s_setprio(0);                          \
    __builtin_amdgcn_s_barrier(); } while (0)

  STA(0); STB(0); STA(1);
  asm volatile("s_waitcnt vmcnt(4)" ::: "memory");
  __builtin_amdgcn_s_barrier();

  for (int u = 0; u < NT; ++u) {
    LDA4(u, 0); LDBall(u);
    if (u + 1 < NT) STB(u + 1);
    PH_BEGIN(); MM24(0); PH_END();
    LDA4(u, 1);
    if (u + 2 < NT) STA(u + 2);
    PH_BEGIN(); MM24(1);
    __builtin_amdgcn_s_setprio(0);
    if (u + 2 < NT) { asm volatile("s_waitcnt vmcnt(4)" ::: "memory"); }
    else            { asm volatile("s_waitcnt vmcnt(0)" ::: "memory"); }
    __builtin_amdgcn_s_barrier();
  }
#undef PH_BEGIN
#undef PH_END

  #pragma unroll
  for (int m = 0; m < 8; ++m)
    #pragma unroll
    for (int nh = 0; nh < 3; ++nh)
      #pragma unroll
      for (int j = 0; j < 4; ++j) {
        long r = arow + wr * 128 + m * 16 + l4 * 4 + j;
        long c = brow + wc * 48 + nh * 16 + l15;
        C[r * Ndim + c] = f2bf(acc[m][nh][j]);
      }
}

// ---------------- 256x128 2-phase bf16 GEMM (out-proj; fp32 out) [R10 proven] -----
__global__ __launch_bounds__(512, 2) void gemm256(const u16* __restrict__ A,
                                                  const u16* __restrict__ B,
                                                  float* __restrict__ C,
                                                  int Ndim, int Kdim) {
  extern __shared__ __align__(16) u16 lds[];
  const int tid = threadIdx.x;
  const int lane = tid & 63, wave = tid >> 6;
  const int wr = wave >> 2, wc = wave & 3;
  const int l15 = lane & 15, l4 = lane >> 4;
  const int gx = gridDim.x;
  int lin = blockIdx.y * gx + blockIdx.x;
  const int xcd = lin & 7, ii = lin >> 3;
  const int bx = xcd * (gx >> 3) + (ii >> 3), by = ii & 7;
  const long arow = (long)by * 256, brow = (long)bx * 128;
  const int NT = Kdim >> 6;

  const int rowt = tid >> 3;
  const int koff = ((tid & 7) ^ (rowt & 7)) * 8;
  const u16* gA[4];
  const u16* gB[2];
  #pragma unroll
  for (int r = 0; r < 4; ++r) gA[r] = A + (size_t)(arow + rowt + r * 64) * Kdim + koff;
  #pragma unroll
  for (int r = 0; r < 2; ++r) gB[r] = B + (size_t)(brow + rowt + r * 64) * Kdim + koff;

  auto STA = [&](int u) {
    u16* d = lds + (u % 3) * 16384 + tid * 8;
    #pragma unroll
    for (int r = 0; r < 4; ++r) gload16(gA[r] + (size_t)u * 64, d + r * 4096);
  };
  auto STB = [&](int u) {
    u16* d = lds + 49152 + (u & 1) * 8192 + tid * 8;
    #pragma unroll
    for (int r = 0; r < 2; ++r) gload16(gB[r] + (size_t)u * 64, d + r * 4096);
  };

  bf16x8 af[4][2], bfr[2][2];
  f32x4 acc[8][2] = {};
  int cks[2];
  #pragma unroll
  for (int kc = 0; kc < 2; ++kc) cks[kc] = (((kc * 4 + l4) ^ (l15 & 7)) * 8);

  auto LDA = [&](int u, int mh) {
    const u16* base = lds + (u % 3) * 16384 + (wr * 128 + mh * 64 + l15) * 64;
    #pragma unroll
    for (int m = 0; m < 4; ++m)
      #pragma unroll
      for (int kc = 0; kc < 2; ++kc)
        af[m][kc] = *(const bf16x8*)(base + m * 1024 + cks[kc]);
  };
  auto LDB = [&](int u) {
    const u16* base = lds + 49152 + (u & 1) * 8192 + (wc * 32 + l15) * 64;
    #pragma unroll
    for (int n = 0; n < 2; ++n)
      #pragma unroll
      for (int kc = 0; kc < 2; ++kc)
        bfr[n][kc] = *(const bf16x8*)(base + n * 1024 + cks[kc]);
  };
  auto MM = [&](int mh) {
    #pragma unroll
    for (int kc = 0; kc < 2; ++kc)
      #pragma unroll
      for (int m = 0; m < 4; ++m)
        #pragma unroll
        for (int n = 0; n < 2; ++n)
          acc[mh * 4 + m][n] =
            __builtin_amdgcn_mfma_f32_16x16x32_bf16(af[m][kc], bfr[n][kc],
                                                    acc[mh * 4 + m][n], 0, 0, 0);
  };

#define PH_BEGIN() do { __builtin_amdgcn_s_barrier();                         \
    asm volatile("s_waitcnt lgkmcnt(0)" ::: "memory");                        \
    __builtin_amdgcn_sched_barrier(0);                                        \
    __builtin_amdgcn_s_setprio(1); } while (0)

  STA(0); STB(0); STA(1); STB(1);
  asm volatile("s_waitcnt vmcnt(6)" ::: "memory");
  __builtin_amdgcn_s_barrier();

  for (int u = 0; u < NT; ++u) {
    LDA(u, 0); LDB(u);
    if (u + 2 < NT) STA(u + 2);
    PH_BEGIN(); MM(0);
    __builtin_amdgcn_s_setprio(0);
    __builtin_amdgcn_s_barrier();
    LDA(u, 1);
    if (u + 2 < NT) STB(u + 2);
    PH_BEGIN(); MM(1);
    __builtin_amdgcn_s_setprio(0);
    if (u + 2 < NT) { asm volatile("s_waitcnt vmcnt(6)" ::: "memory"); }
    else if (u + 1 < NT) { asm volatile("s_waitcnt vmcnt(0)" ::: "memory"); }
    __builtin_amdgcn_s_barrier();
  }
#undef PH_BEGIN

  #pragma unroll
  for (int M = 0; M < 8; ++M)
    #pragma unroll
    for (int n = 0; n < 2; ++n)
      #pragma unroll
      for (int j = 0; j < 4; ++j) {
        long r = arow + wr * 128 + M * 16 + l4 * 4 + j;
        long c = brow + wc * 32 + n * 16 + l15;
        C[r * Ndim + c] = acc[M][n][j];
      }
}

// ---------------- fused per-head LayerNorm + RoPE, bf16 in/out (q,k only; v read in-place) ----
__global__ __launch_bounds__(256) void ln_rope_kernel(
    const u16* __restrict__ qkv, const int* __restrict__ pos,
    const float* __restrict__ qw, const float* __restrict__ qb2,
    const float* __restrict__ kw, const float* __restrict__ kb2,
    u16* __restrict__ qo, u16* __restrict__ ko, int T) {
  const int hh = blockIdx.x;          // [0,64): q heads then k heads
  const int t0 = blockIdx.y * 16 + (threadIdx.x >> 6) * 4;
  const int lane = threadIdx.x & 63;
  bool isq = hh < 32;
  int hl = isq ? hh : hh - 32;
  const float* wp = (isq ? qw : kw) + hl * 128;
  const float* bp = (isq ? qb2 : kb2) + hl * 128;
  float w1 = wp[lane], w2 = wp[lane + 64];
  float b1 = bp[lane], b2 = bp[lane + 64];
  float invf = exp2f((float)lane * (-13.287712379549449f / 64.0f));
  u16* obase = (isq ? qo : ko) + (size_t)hl * T * 128;
  const float sc = isq ? 0.08838834764831845f : 1.0f;   // 1/sqrt(128) folded into q
  #pragma unroll
  for (int i = 0; i < 4; ++i) {
    int t = t0 + i;
    const u16* src = qkv + (size_t)t * 12288 + hh * 128;
    float x1 = bf2f(src[lane]), x2 = bf2f(src[lane + 64]);
    float s = x1 + x2;
    #pragma unroll
    for (int off = 32; off; off >>= 1) s += __shfl_xor(s, off);
    float mu = s * (1.0f / 128.0f);
    float d1 = x1 - mu, d2 = x2 - mu;
    float vs = d1 * d1 + d2 * d2;
    #pragma unroll
    for (int off = 32; off; off >>= 1) vs += __shfl_xor(vs, off);
    float rstd = rsqrtf(vs * (1.0f / 128.0f) + 1e-5f);
    float y1 = d1 * rstd * w1 + b1;
    float y2 = d2 * rstd * w2 + b2;
    float fr = (float)pos[t] * invf;
    float sn, cs;
    __sincosf(fr, &sn, &cs);
    float o1 = (y1 * cs - y2 * sn) * sc;
    float o2 = (y2 * cs + y1 * sn) * sc;
    u16* dst = obase + (size_t)t * 128;
    dst[lane] = f2bf(o1); dst[lane + 64] = f2bf(o2);
  }
}

// ---------------- flash attention (causal): 512 one-q-tile blocks [R13-proven mapping] ----
// bid<256 -> LONG qt=15-(bid>>5); bid>=256 -> SHORT qt=(bid-256)>>5. Round-robin dispatch
// gives CU c bids {c, c+256}: ntile sum = 36 uniform (R13/R14 A/B evidence).
// V is read DIRECTLY from qkv_bf (row stride 12288, head col (64+h)*128) - no v-copy pass.
__global__ __launch_bounds__(512, 2) void flash_kernel(
    const u16* __restrict__ qb, const u16* __restrict__ kb,
    const u16* __restrict__ qkvb, u16* __restrict__ attn, int T) {
  extern __shared__ __align__(16) u16 flds[];
  u16* const Ks = flds;            // 64x128 swizzled (8192 u16)
  u16* const Vt = flds + 8192;     // 128x64 transposed swizzled (8192 u16)
  u16* const Ps = flds + 16384;    // 8 x (16x64) per-wave (8192 u16)
  const int tid = threadIdx.x;
  const int lane = tid & 63, wave = tid >> 6;
  const int l15 = lane & 15, l4 = lane >> 4;
  const int bid = blockIdx.x;
  const int nqt = T >> 7;
  const int h = bid & 31;
  const int qt = (bid < 256) ? (nqt - 1 - (bid >> 5)) : ((bid - 256) >> 5);
  const int qbase = qt * 128;
  const u16* Q  = qb + (size_t)h * T * 128;
  const u16* Kp = kb + (size_t)h * T * 128;
  const u16* Vp = qkvb + (size_t)(64 + h) * 128;   // row t at Vp[t*12288 + d]
  const int rK = tid >> 4, d8k = (tid & 15) * 8;
  const int rv = tid & 63, dv0 = (tid >> 6) * 8;
  u16* const Pw = Ps + wave * 1024;

  const int r0g = qbase + wave * 16;   // this wave's 16 q-rows
  bf16x8 qf[4];
  #pragma unroll
  for (int kc = 0; kc < 4; ++kc)
    qf[kc] = *(const bf16x8*)&Q[(size_t)(r0g + l15) * 128 + kc * 32 + l4 * 8];

  float m_st[4], l_st[4];
  f32x4 o[8] = {};
  #pragma unroll
  for (int j = 0; j < 4; ++j) { m_st[j] = -1e30f; l_st[j] = 0.0f; }

  const int ntile = 2 * qt + 2;
  uint4 kr[2], vr[2];
  #pragma unroll
  for (int c = 0; c < 2; ++c) {
    kr[c] = *(const uint4*)&Kp[(size_t)(rK + 32 * c) * 128 + d8k];
    vr[c] = *(const uint4*)&Vp[(size_t)rv * 12288 + dv0 + 64 * c];
  }
  for (int kt = 0; kt < ntile; ++kt) {
    const int kbase = kt * 64;
    #pragma unroll
    for (int c = 0; c < 2; ++c) {
      *(uint4*)&Ks[swz128i(rK + 32 * c, d8k)] = kr[c];
      const u16* pv = (const u16*)&vr[c];
      #pragma unroll
      for (int j = 0; j < 8; ++j) Vt[swz64i(dv0 + 64 * c + j, rv)] = pv[j];
    }
    __syncthreads();
    if (kt + 1 < ntile) {
      const int nb = kbase + 64;
      #pragma unroll
      for (int c = 0; c < 2; ++c) {
        kr[c] = *(const uint4*)&Kp[(size_t)(nb + rK + 32 * c) * 128 + d8k];
        vr[c] = *(const uint4*)&Vp[(size_t)(nb + rv) * 12288 + dv0 + 64 * c];
      }
    }
    if (kbase <= r0g + 15) {
      f32x4 s[4] = {};
      __builtin_amdgcn_s_setprio(1);
      #pragma unroll
      for (int kc = 0; kc < 4; ++kc)
        #pragma unroll
        for (int nj = 0; nj < 4; ++nj) {
          bf16x8 kf = *(const bf16x8*)&Ks[swz128i(nj * 16 + l15, kc * 32 + l4 * 8)];
          s[nj] = __builtin_amdgcn_mfma_f32_16x16x32_bf16(qf[kc], kf, s[nj], 0, 0, 0);
        }
      __builtin_amdgcn_s_setprio(0);
      if (kbase + 63 > r0g) {
        #pragma unroll
        for (int nj = 0; nj < 4; ++nj)
          #pragma unroll
          for (int j = 0; j < 4; ++j) {
            int r = r0g + l4 * 4 + j;
            int cc = kbase + nj * 16 + l15;
            if (cc > r) s[nj][j] = -1e30f;
          }
      }
      float vmax[4];
      float dmax = -1e30f;
      #pragma unroll
      for (int j = 0; j < 4; ++j) {
        float v = fmaxf(fmaxf(s[0][j], s[1][j]), fmaxf(s[2][j], s[3][j]));
        #pragma unroll
        for (int off = 1; off < 16; off <<= 1) v = fmaxf(v, __shfl_xor(v, off));
        vmax[j] = v;
        dmax = fmaxf(dmax, v - m_st[j]);
      }
      if (!__all(dmax <= 8.0f)) {
        #pragma unroll
        for (int j = 0; j < 4; ++j) {
          float mn = fmaxf(m_st[j], vmax[j]);
          float scl = __expf(m_st[j] - mn);
          m_st[j] = mn;
          l_st[j] *= scl;
          #pragma unroll
          for (int nf = 0; nf < 8; ++nf) o[nf][j] *= scl;
        }
      }
      float sum[4] = {0.f, 0.f, 0.f, 0.f};
      #pragma unroll
      for (int nj = 0; nj < 4; ++nj)
        #pragma unroll
        for (int j = 0; j < 4; ++j) {
          float p = __expf(s[nj][j] - m_st[j]);
          s[nj][j] = p;
          sum[j] += p;
        }
      #pragma unroll
      for (int j = 0; j < 4; ++j) {
        #pragma unroll
        for (int off = 1; off < 16; off <<= 1) sum[j] += __shfl_xor(sum[j], off);
        l_st[j] += sum[j];
      }
      #pragma unroll
      for (int nj = 0; nj < 4; ++nj)
        #pragma unroll
        for (int j = 0; j < 4; ++j)
          Pw[swz64i(l4 * 4 + j, nj * 16 + l15)] = f2bf(s[nj][j]);
      asm volatile("s_waitcnt lgkmcnt(0)" ::: "memory");
      __builtin_amdgcn_sched_barrier(0);
      __builtin_amdgcn_s_setprio(1);
      #pragma unroll
      for (int kc = 0; kc < 2; ++kc) {
        bf16x8 pf = *(const bf16x8*)&Pw[swz64i(l15, kc * 32 + l4 * 8)];
        #pragma unroll
        for (int nf = 0; nf < 8; ++nf) {
          bf16x8 vf = *(const bf16x8*)&Vt[swz64i(nf * 16 + l15, kc * 32 + l4 * 8)];
          o[nf] = __builtin_amdgcn_mfma_f32_16x16x32_bf16(pf, vf, o[nf], 0, 0, 0);
        }
      }
      __builtin_amdgcn_s_setprio(0);
    }
    __syncthreads();
  }
  float rl[4];
  #pragma unroll
  for (int j = 0; j < 4; ++j) rl[j] = 1.0f / l_st[j];
  #pragma unroll
  for (int nf = 0; nf < 8; ++nf)
    #pragma unroll
    for (int j = 0; j < 4; ++j) {
      int r = r0g + l4 * 4 + j;
      int cc = h * 128 + nf * 16 + l15;
      attn[(size_t)r * 4096 + cc] = f2bf(o[nf][j] * rl[j]);
    }
}

// ---------------- launch ----------------
extern "C" void kernel_launch(void* const* d_in, const int* in_sizes, int n_in,
                              void* d_out, int out_size, void* d_ws, size_t ws_size,
                              hipStream_t stream) {
  const int* positions = (const int*)d_in[0];
  const float* hidden  = (const float*)d_in[1];
  const float* w_qkv   = (const float*)d_in[2];
  const float* w_o     = (const float*)d_in[3];
  const float* qnw     = (const float*)d_in[4];
  const float* qnb     = (const float*)d_in[5];
  const float* knw     = (const float*)d_in[6];
  const float* knb     = (const float*)d_in[7];
  float* out = (float*)d_out;

  const int T = in_sizes[0];           // 2048
  const int HID = 4096, NQKV = 12288, H = 32;

  char* ws = (char*)d_ws;
  u16* hid_bf  = (u16*)ws;
  u16* wreg    = (u16*)(ws + (size_t)T * HID * 2);
  u16* qkv_bf  = (u16*)(ws + (size_t)T * HID * 2 + (size_t)NQKV * HID * 2);

  u16* q_bf  = wreg;                                 // [H][T][128]
  u16* k_bf  = q_bf + (size_t)H * T * 128;
  u16* at_bf = k_bf + (size_t)H * T * 128;           // [T][H*128]
  u16* wo_bf = at_bf + (size_t)T * 4096;             // [4096][4096]

  hipFuncSetAttribute(reinterpret_cast<const void*>(&gemm192),
                      hipFuncAttributeMaxDynamicSharedMemorySize, 147456);
  hipFuncSetAttribute(reinterpret_cast<const void*>(&gemm256),
                      hipFuncAttributeMaxDynamicSharedMemorySize, 131072);
  hipFuncSetAttribute(reinterpret_cast<const void*>(&flash_kernel),
                      hipFuncAttributeMaxDynamicSharedMemorySize, 49152);

  cvt_bf16_kernel<<<2048, 256, 0, stream>>>(hidden, hid_bf, (long)T * HID / 4);
  cvt_bf16_kernel<<<4096, 256, 0, stream>>>(w_qkv, wreg, (long)NQKV * HID / 4);
  gemm192<<<dim3(NQKV / 192, T / 256), 512, 147456, stream>>>(hid_bf, wreg, qkv_bf, NQKV, HID);
  ln_rope_kernel<<<dim3(64, T / 16), 256, 0, stream>>>(qkv_bf, positions, qnw, qnb, knw, knb,
                                                       q_bf, k_bf, T);
  cvt_bf16_kernel<<<2048, 256, 0, stream>>>(w_o, wo_bf, (long)HID * HID / 4);
  flash_kernel<<<512, 512, 49152, stream>>>(q_bf, k_bf, qkv_bf, at_bf, T);
  gemm256<<<dim3(HID / 128, T / 256), 512, 131072, stream>>>(at_bf, wo_bf, out, HID, HID);
}

// Round 16
// 475.538 us; speedup vs baseline: 1.0886x; 1.0478x over previous
//
#include <hip/hip_runtime.h>
#include <cstdint>

typedef unsigned short u16;
typedef __attribute__((ext_vector_type(8))) __bf16 bf16x8;
typedef __attribute__((ext_vector_type(4))) float f32x4;

__device__ __forceinline__ u16 f2bf(float f) {
  unsigned int u = __builtin_bit_cast(unsigned int, f);
  unsigned int r = (u + 0x7fffu + ((u >> 16) & 1u)) >> 16;
  return (u16)r;
}
__device__ __forceinline__ float bf2f(u16 u) {
  return __builtin_bit_cast(float, (unsigned int)u << 16);
}

// async global->LDS, 16B per lane. LDS dest must be linear in lane (wave base + lane*16).
__device__ __forceinline__ void gload16(const u16* g, u16* l) {
  __builtin_amdgcn_global_load_lds((const __attribute__((address_space(1))) void*)g,
                                   (__attribute__((address_space(3))) void*)l, 16, 0, 0);
}

// XOR-swizzle helpers for flash kernel LDS.
__device__ __forceinline__ int swz64i(int row, int col) {   // 64 u16 cols per row
  return row * 64 + (((col & 0x38) ^ ((row & 7) << 3)) | (col & 7));
}
__device__ __forceinline__ int swz128i(int row, int col) {  // 128 u16 cols per row
  return row * 128 + (((col & 0x78) ^ ((row & 7) << 3)) | (col & 7));
}

// ---------------- fp32 -> bf16 conversion ----------------
__global__ __launch_bounds__(256) void cvt_bf16_kernel(const float* __restrict__ in,
                                                       u16* __restrict__ out, long n4) {
  long i = (long)blockIdx.x * 256 + threadIdx.x;
  long stride = (long)gridDim.x * 256;
  const float4* in4 = (const float4*)in;
  uint2* out2 = (uint2*)out;
  for (long k = i; k < n4; k += stride) {
    float4 v = in4[k];
    uint2 o;
    o.x = (unsigned int)f2bf(v.x) | ((unsigned int)f2bf(v.y) << 16);
    o.y = (unsigned int)f2bf(v.z) | ((unsigned int)f2bf(v.w) << 16);
    out2[k] = o;
  }
}

// ---------------- 256x192 2-phase m-split bf16 GEMM (QKV; bf16 out) [R10 proven] ----
__global__ __launch_bounds__(512, 2) void gemm192(const u16* __restrict__ A,
                                                  const u16* __restrict__ B,
                                                  u16* __restrict__ C,
                                                  int Ndim, int Kdim) {
  extern __shared__ __align__(16) u16 lds[];   // A: 3*16384 u16 @0, B: 2*12288 u16 @49152
  const int tid = threadIdx.x;
  const int lane = tid & 63, wave = tid >> 6;
  const int wr = wave >> 2, wc = wave & 3;
  const int l15 = lane & 15, l4 = lane >> 4;
  const int gx = gridDim.x;
  int lin = blockIdx.y * gx + blockIdx.x;
  const int xcd = lin & 7, ii = lin >> 3;
  const int bx = xcd * (gx >> 3) + (ii >> 3), by = ii & 7;
  const long arow = (long)by * 256, brow = (long)bx * 192;
  const int NT = Kdim >> 6;

  const int rowt = tid >> 3;
  const int koff = ((tid & 7) ^ (rowt & 7)) * 8;
  const u16* gA[4];
  const u16* gB[3];
  #pragma unroll
  for (int r = 0; r < 4; ++r) gA[r] = A + (size_t)(arow + rowt + r * 64) * Kdim + koff;
  #pragma unroll
  for (int r = 0; r < 3; ++r) gB[r] = B + (size_t)(brow + rowt + r * 64) * Kdim + koff;
  u16* const ldsB = lds + 49152;

  auto STA = [&](int u) {
    u16* d = lds + (u % 3) * 16384 + tid * 8;
    #pragma unroll
    for (int r = 0; r < 4; ++r) gload16(gA[r] + (size_t)u * 64, d + r * 4096);
  };
  auto STB = [&](int u) {
    u16* d = ldsB + (u & 1) * 12288 + tid * 8;
    #pragma unroll
    for (int r = 0; r < 3; ++r) gload16(gB[r] + (size_t)u * 64, d + r * 4096);
  };

  bf16x8 af[4][2], bfr[3][2];
  f32x4 acc[8][3] = {};
  int cks[2];
  #pragma unroll
  for (int kc = 0; kc < 2; ++kc) cks[kc] = (((kc * 4 + l4) ^ (l15 & 7)) * 8);

  auto LDA4 = [&](int u, int mh) {
    const u16* base = lds + (u % 3) * 16384 + (wr * 128 + mh * 64 + l15) * 64;
    #pragma unroll
    for (int m = 0; m < 4; ++m)
      #pragma unroll
      for (int kc = 0; kc < 2; ++kc)
        af[m][kc] = *(const bf16x8*)(base + m * 1024 + cks[kc]);
  };
  auto LDBall = [&](int u) {
    const u16* base = ldsB + (u & 1) * 12288 + (wc * 48 + l15) * 64;
    #pragma unroll
    for (int nh = 0; nh < 3; ++nh)
      #pragma unroll
      for (int kc = 0; kc < 2; ++kc)
        bfr[nh][kc] = *(const bf16x8*)(base + nh * 1024 + cks[kc]);
  };
  auto MM24 = [&](int mh) {
    #pragma unroll
    for (int kc = 0; kc < 2; ++kc)
      #pragma unroll
      for (int m = 0; m < 4; ++m)
        #pragma unroll
        for (int nh = 0; nh < 3; ++nh)
          acc[mh * 4 + m][nh] = __builtin_amdgcn_mfma_f32_16x16x32_bf16(
              af[m][kc], bfr[nh][kc], acc[mh * 4 + m][nh], 0, 0, 0);
  };

#define PH_BEGIN() do { __builtin_amdgcn_s_barrier();                         \
    asm volatile("s_waitcnt lgkmcnt(0)" ::: "memory");                        \
    __builtin_amdgcn_sched_barrier(0);                                        \
    __builtin_amdgcn_s_setprio(1); } while (0)
#define PH_END() do { __builtin_amdgcn_s_setprio(0);                          \
    __builtin_amdgcn_s_barrier(); } while (0)

  STA(0); STB(0); STA(1);
  asm volatile("s_waitcnt vmcnt(4)" ::: "memory");
  __builtin_amdgcn_s_barrier();

  for (int u = 0; u < NT; ++u) {
    LDA4(u, 0); LDBall(u);
    if (u + 1 < NT) STB(u + 1);
    PH_BEGIN(); MM24(0); PH_END();
    LDA4(u, 1);
    if (u + 2 < NT) STA(u + 2);
    PH_BEGIN(); MM24(1);
    __builtin_amdgcn_s_setprio(0);
    if (u + 2 < NT) { asm volatile("s_waitcnt vmcnt(4)" ::: "memory"); }
    else            { asm volatile("s_waitcnt vmcnt(0)" ::: "memory"); }
    __builtin_amdgcn_s_barrier();
  }
#undef PH_BEGIN
#undef PH_END

  #pragma unroll
  for (int m = 0; m < 8; ++m)
    #pragma unroll
    for (int nh = 0; nh < 3; ++nh)
      #pragma unroll
      for (int j = 0; j < 4; ++j) {
        long r = arow + wr * 128 + m * 16 + l4 * 4 + j;
        long c = brow + wc * 48 + nh * 16 + l15;
        C[r * Ndim + c] = f2bf(acc[m][nh][j]);
      }
}

// ---------------- 256x128 2-phase bf16 GEMM (out-proj; fp32 out) [R10 proven] -----
__global__ __launch_bounds__(512, 2) void gemm256(const u16* __restrict__ A,
                                                  const u16* __restrict__ B,
                                                  float* __restrict__ C,
                                                  int Ndim, int Kdim) {
  extern __shared__ __align__(16) u16 lds[];
  const int tid = threadIdx.x;
  const int lane = tid & 63, wave = tid >> 6;
  const int wr = wave >> 2, wc = wave & 3;
  const int l15 = lane & 15, l4 = lane >> 4;
  const int gx = gridDim.x;
  int lin = blockIdx.y * gx + blockIdx.x;
  const int xcd = lin & 7, ii = lin >> 3;
  const int bx = xcd * (gx >> 3) + (ii >> 3), by = ii & 7;
  const long arow = (long)by * 256, brow = (long)bx * 128;
  const int NT = Kdim >> 6;

  const int rowt = tid >> 3;
  const int koff = ((tid & 7) ^ (rowt & 7)) * 8;
  const u16* gA[4];
  const u16* gB[2];
  #pragma unroll
  for (int r = 0; r < 4; ++r) gA[r] = A + (size_t)(arow + rowt + r * 64) * Kdim + koff;
  #pragma unroll
  for (int r = 0; r < 2; ++r) gB[r] = B + (size_t)(brow + rowt + r * 64) * Kdim + koff;

  auto STA = [&](int u) {
    u16* d = lds + (u % 3) * 16384 + tid * 8;
    #pragma unroll
    for (int r = 0; r < 4; ++r) gload16(gA[r] + (size_t)u * 64, d + r * 4096);
  };
  auto STB = [&](int u) {
    u16* d = lds + 49152 + (u & 1) * 8192 + tid * 8;
    #pragma unroll
    for (int r = 0; r < 2; ++r) gload16(gB[r] + (size_t)u * 64, d + r * 4096);
  };

  bf16x8 af[4][2], bfr[2][2];
  f32x4 acc[8][2] = {};
  int cks[2];
  #pragma unroll
  for (int kc = 0; kc < 2; ++kc) cks[kc] = (((kc * 4 + l4) ^ (l15 & 7)) * 8);

  auto LDA = [&](int u, int mh) {
    const u16* base = lds + (u % 3) * 16384 + (wr * 128 + mh * 64 + l15) * 64;
    #pragma unroll
    for (int m = 0; m < 4; ++m)
      #pragma unroll
      for (int kc = 0; kc < 2; ++kc)
        af[m][kc] = *(const bf16x8*)(base + m * 1024 + cks[kc]);
  };
  auto LDB = [&](int u) {
    const u16* base = lds + 49152 + (u & 1) * 8192 + (wc * 32 + l15) * 64;
    #pragma unroll
    for (int n = 0; n < 2; ++n)
      #pragma unroll
      for (int kc = 0; kc < 2; ++kc)
        bfr[n][kc] = *(const bf16x8*)(base + n * 1024 + cks[kc]);
  };
  auto MM = [&](int mh) {
    #pragma unroll
    for (int kc = 0; kc < 2; ++kc)
      #pragma unroll
      for (int m = 0; m < 4; ++m)
        #pragma unroll
        for (int n = 0; n < 2; ++n)
          acc[mh * 4 + m][n] =
            __builtin_amdgcn_mfma_f32_16x16x32_bf16(af[m][kc], bfr[n][kc],
                                                    acc[mh * 4 + m][n], 0, 0, 0);
  };

#define PH_BEGIN() do { __builtin_amdgcn_s_barrier();                         \
    asm volatile("s_waitcnt lgkmcnt(0)" ::: "memory");                        \
    __builtin_amdgcn_sched_barrier(0);                                        \
    __builtin_amdgcn_s_setprio(1); } while (0)

  STA(0); STB(0); STA(1); STB(1);
  asm volatile("s_waitcnt vmcnt(6)" ::: "memory");
  __builtin_amdgcn_s_barrier();

  for (int u = 0; u < NT; ++u) {
    LDA(u, 0); LDB(u);
    if (u + 2 < NT) STA(u + 2);
    PH_BEGIN(); MM(0);
    __builtin_amdgcn_s_setprio(0);
    __builtin_amdgcn_s_barrier();
    LDA(u, 1);
    if (u + 2 < NT) STB(u + 2);
    PH_BEGIN(); MM(1);
    __builtin_amdgcn_s_setprio(0);
    if (u + 2 < NT) { asm volatile("s_waitcnt vmcnt(6)" ::: "memory"); }
    else if (u + 1 < NT) { asm volatile("s_waitcnt vmcnt(0)" ::: "memory"); }
    __builtin_amdgcn_s_barrier();
  }
#undef PH_BEGIN

  #pragma unroll
  for (int M = 0; M < 8; ++M)
    #pragma unroll
    for (int n = 0; n < 2; ++n)
      #pragma unroll
      for (int j = 0; j < 4; ++j) {
        long r = arow + wr * 128 + M * 16 + l4 * 4 + j;
        long c = brow + wc * 32 + n * 16 + l15;
        C[r * Ndim + c] = acc[M][n][j];
      }
}

// ---------------- fused per-head LayerNorm + RoPE, bf16 in/out (batched 4 rows/wave) ----
__global__ __launch_bounds__(256) void ln_rope_kernel(
    const u16* __restrict__ qkv, const int* __restrict__ pos,
    const float* __restrict__ qw, const float* __restrict__ qb2,
    const float* __restrict__ kw, const float* __restrict__ kb2,
    u16* __restrict__ qo, u16* __restrict__ ko, u16* __restrict__ vo, int T) {
  const int hh = blockIdx.x;
  const int t0 = blockIdx.y * 16 + (threadIdx.x >> 6) * 4;
  const int lane = threadIdx.x & 63;
  if (hh >= 64) {   // v: pure bit-copy [t][hh*128+d] -> [h][t][d]  (scalar, R11-proven)
    #pragma unroll
    for (int i = 0; i < 4; ++i) {
      int t = t0 + i;
      const u16* src = qkv + (size_t)t * 12288 + hh * 128;
      u16* dst = vo + ((size_t)(hh - 64) * T + t) * 128;
      dst[lane] = src[lane];
      dst[lane + 64] = src[lane + 64];
    }
    return;
  }
  bool isq = hh < 32;
  int hl = isq ? hh : hh - 32;
  const float* wp = (isq ? qw : kw) + hl * 128;
  const float* bp = (isq ? qb2 : kb2) + hl * 128;
  float w1 = wp[lane], w2 = wp[lane + 64];
  float b1 = bp[lane], b2 = bp[lane + 64];
  float invf = exp2f((float)lane * (-13.287712379549449f / 64.0f));
  u16* obase = (isq ? qo : ko) + (size_t)hl * T * 128;
  const float sc = isq ? 0.08838834764831845f : 1.0f;   // 1/sqrt(128) folded into q
  #pragma unroll
  for (int i = 0; i < 4; ++i) {
    int t = t0 + i;
    const u16* src = qkv + (size_t)t * 12288 + hh * 128;
    float x1 = bf2f(src[lane]), x2 = bf2f(src[lane + 64]);
    float s = x1 + x2;
    #pragma unroll
    for (int off = 32; off; off >>= 1) s += __shfl_xor(s, off);
    float mu = s * (1.0f / 128.0f);
    float d1 = x1 - mu, d2 = x2 - mu;
    float vs = d1 * d1 + d2 * d2;
    #pragma unroll
    for (int off = 32; off; off >>= 1) vs += __shfl_xor(vs, off);
    float rstd = rsqrtf(vs * (1.0f / 128.0f) + 1e-5f);
    float y1 = d1 * rstd * w1 + b1;
    float y2 = d2 * rstd * w2 + b2;
    float fr = (float)pos[t] * invf;
    float sn, cs;
    __sincosf(fr, &sn, &cs);
    float o1 = (y1 * cs - y2 * sn) * sc;
    float o2 = (y2 * cs + y1 * sn) * sc;
    u16* dst = obase + (size_t)t * 128;
    dst[lane] = f2bf(o1); dst[lane + 64] = f2bf(o2);
  }
}

// ---------------- flash attention (causal) + fused w_o conversion ----------
// bids 0..511: R13-proven flash mapping (bid<256 -> LONG qt=15-(bid>>5);
// else SHORT qt=(bid-256)>>5; round-robin gives each CU one long + one short = 36 tiles).
// bids 512..767: pure grid-stride fp32->bf16 convert of w_o — co-resides as the 3rd
// block per CU (3 x 48KB LDS = 144 <= 160KB; 24 waves), streaming HBM that the flash
// blocks don't use. No barriers on that path (whole-block divergence).
__global__ __launch_bounds__(512, 2) void flash_kernel(
    const u16* __restrict__ qb, const u16* __restrict__ kb,
    const u16* __restrict__ vb, u16* __restrict__ attn, int T,
    const float* __restrict__ wo, u16* __restrict__ wo_bf) {
  extern __shared__ __align__(16) u16 flds[];
  const int tid = threadIdx.x;
  const int bid = blockIdx.x;
  if (bid >= 512) {   // ---- cvt_wo path ----
    const long n4 = (long)4096 * 4096 / 4;
    long i = (long)(bid - 512) * 512 + tid;
    const long stride = 256 * 512;
    const float4* in4 = (const float4*)wo;
    uint2* out2 = (uint2*)wo_bf;
    for (long k = i; k < n4; k += stride) {
      float4 v = in4[k];
      uint2 o;
      o.x = (unsigned int)f2bf(v.x) | ((unsigned int)f2bf(v.y) << 16);
      o.y = (unsigned int)f2bf(v.z) | ((unsigned int)f2bf(v.w) << 16);
      out2[k] = o;
    }
    return;
  }
  u16* const Ks = flds;            // 64x128 swizzled (8192 u16)
  u16* const Vt = flds + 8192;     // 128x64 transposed swizzled (8192 u16)
  u16* const Ps = flds + 16384;    // 8 x (16x64) per-wave (8192 u16)
  const int lane = tid & 63, wave = tid >> 6;
  const int l15 = lane & 15, l4 = lane >> 4;
  const int nqt = T >> 7;
  const int h = bid & 31;
  const int qt = (bid < 256) ? (nqt - 1 - (bid >> 5)) : ((bid - 256) >> 5);
  const int qbase = qt * 128;
  const u16* Q  = qb + (size_t)h * T * 128;
  const u16* Kp = kb + (size_t)h * T * 128;
  const u16* Vp = vb + (size_t)h * T * 128;
  const int rK = tid >> 4, d8k = (tid & 15) * 8;
  const int rv = tid & 63, dv0 = (tid >> 6) * 8;
  u16* const Pw = Ps + wave * 1024;

  const int r0g = qbase + wave * 16;   // this wave's 16 q-rows
  bf16x8 qf[4];
  #pragma unroll
  for (int kc = 0; kc < 4; ++kc)
    qf[kc] = *(const bf16x8*)&Q[(size_t)(r0g + l15) * 128 + kc * 32 + l4 * 8];

  float m_st[4], l_st[4];
  f32x4 o[8] = {};
  #pragma unroll
  for (int j = 0; j < 4; ++j) { m_st[j] = -1e30f; l_st[j] = 0.0f; }

  const int ntile = 2 * qt + 2;
  uint4 kr[2], vr[2];
  #pragma unroll
  for (int c = 0; c < 2; ++c) {
    kr[c] = *(const uint4*)&Kp[(size_t)(rK + 32 * c) * 128 + d8k];
    vr[c] = *(const uint4*)&Vp[(size_t)rv * 128 + dv0 + 64 * c];
  }
  for (int kt = 0; kt < ntile; ++kt) {
    const int kbase = kt * 64;
    #pragma unroll
    for (int c = 0; c < 2; ++c) {
      *(uint4*)&Ks[swz128i(rK + 32 * c, d8k)] = kr[c];
      const u16* pv = (const u16*)&vr[c];
      #pragma unroll
      for (int j = 0; j < 8; ++j) Vt[swz64i(dv0 + 64 * c + j, rv)] = pv[j];
    }
    __syncthreads();
    if (kt + 1 < ntile) {
      const int nb = kbase + 64;
      #pragma unroll
      for (int c = 0; c < 2; ++c) {
        kr[c] = *(const uint4*)&Kp[(size_t)(nb + rK + 32 * c) * 128 + d8k];
        vr[c] = *(const uint4*)&Vp[(size_t)(nb + rv) * 128 + dv0 + 64 * c];
      }
    }
    if (kbase <= r0g + 15) {
      f32x4 s[4] = {};
      __builtin_amdgcn_s_setprio(1);
      #pragma unroll
      for (int kc = 0; kc < 4; ++kc)
        #pragma unroll
        for (int nj = 0; nj < 4; ++nj) {
          bf16x8 kf = *(const bf16x8*)&Ks[swz128i(nj * 16 + l15, kc * 32 + l4 * 8)];
          s[nj] = __builtin_amdgcn_mfma_f32_16x16x32_bf16(qf[kc], kf, s[nj], 0, 0, 0);
        }
      __builtin_amdgcn_s_setprio(0);
      if (kbase + 63 > r0g) {
        #pragma unroll
        for (int nj = 0; nj < 4; ++nj)
          #pragma unroll
          for (int j = 0; j < 4; ++j) {
            int r = r0g + l4 * 4 + j;
            int cc = kbase + nj * 16 + l15;
            if (cc > r) s[nj][j] = -1e30f;
          }
      }
      float vmax[4];
      float dmax = -1e30f;
      #pragma unroll
      for (int j = 0; j < 4; ++j) {
        float v = fmaxf(fmaxf(s[0][j], s[1][j]), fmaxf(s[2][j], s[3][j]));
        #pragma unroll
        for (int off = 1; off < 16; off <<= 1) v = fmaxf(v, __shfl_xor(v, off));
        vmax[j] = v;
        dmax = fmaxf(dmax, v - m_st[j]);
      }
      if (!__all(dmax <= 8.0f)) {
        #pragma unroll
        for (int j = 0; j < 4; ++j) {
          float mn = fmaxf(m_st[j], vmax[j]);
          float scl = __expf(m_st[j] - mn);
          m_st[j] = mn;
          l_st[j] *= scl;
          #pragma unroll
          for (int nf = 0; nf < 8; ++nf) o[nf][j] *= scl;
        }
      }
      float sum[4] = {0.f, 0.f, 0.f, 0.f};
      #pragma unroll
      for (int nj = 0; nj < 4; ++nj)
        #pragma unroll
        for (int j = 0; j < 4; ++j) {
          float p = __expf(s[nj][j] - m_st[j]);
          s[nj][j] = p;
          sum[j] += p;
        }
      #pragma unroll
      for (int j = 0; j < 4; ++j) {
        #pragma unroll
        for (int off = 1; off < 16; off <<= 1) sum[j] += __shfl_xor(sum[j], off);
        l_st[j] += sum[j];
      }
      #pragma unroll
      for (int nj = 0; nj < 4; ++nj)
        #pragma unroll
        for (int j = 0; j < 4; ++j)
          Pw[swz64i(l4 * 4 + j, nj * 16 + l15)] = f2bf(s[nj][j]);
      asm volatile("s_waitcnt lgkmcnt(0)" ::: "memory");
      __builtin_amdgcn_sched_barrier(0);
      __builtin_amdgcn_s_setprio(1);
      #pragma unroll
      for (int kc = 0; kc < 2; ++kc) {
        bf16x8 pf = *(const bf16x8*)&Pw[swz64i(l15, kc * 32 + l4 * 8)];
        #pragma unroll
        for (int nf = 0; nf < 8; ++nf) {
          bf16x8 vf = *(const bf16x8*)&Vt[swz64i(nf * 16 + l15, kc * 32 + l4 * 8)];
          o[nf] = __builtin_amdgcn_mfma_f32_16x16x32_bf16(pf, vf, o[nf], 0, 0, 0);
        }
      }
      __builtin_amdgcn_s_setprio(0);
    }
    __syncthreads();
  }
  float rl[4];
  #pragma unroll
  for (int j = 0; j < 4; ++j) rl[j] = 1.0f / l_st[j];
  #pragma unroll
  for (int nf = 0; nf < 8; ++nf)
    #pragma unroll
    for (int j = 0; j < 4; ++j) {
      int r = r0g + l4 * 4 + j;
      int cc = h * 128 + nf * 16 + l15;
      attn[(size_t)r * 4096 + cc] = f2bf(o[nf][j] * rl[j]);
    }
}

// ---------------- launch ----------------
extern "C" void kernel_launch(void* const* d_in, const int* in_sizes, int n_in,
                              void* d_out, int out_size, void* d_ws, size_t ws_size,
                              hipStream_t stream) {
  const int* positions = (const int*)d_in[0];
  const float* hidden  = (const float*)d_in[1];
  const float* w_qkv   = (const float*)d_in[2];
  const float* w_o     = (const float*)d_in[3];
  const float* qnw     = (const float*)d_in[4];
  const float* qnb     = (const float*)d_in[5];
  const float* knw     = (const float*)d_in[6];
  const float* knb     = (const float*)d_in[7];
  float* out = (float*)d_out;

  const int T = in_sizes[0];           // 2048
  const int HID = 4096, NQKV = 12288, H = 32;

  char* ws = (char*)d_ws;
  u16* hid_bf  = (u16*)ws;
  u16* wreg    = (u16*)(ws + (size_t)T * HID * 2);
  u16* qkv_bf  = (u16*)(ws + (size_t)T * HID * 2 + (size_t)NQKV * HID * 2);

  u16* q_bf  = wreg;                                 // [H][T][128]
  u16* k_bf  = q_bf + (size_t)H * T * 128;
  u16* v_bf  = k_bf + (size_t)H * T * 128;
  u16* at_bf = v_bf + (size_t)H * T * 128;           // [T][H*128]
  u16* wo_bf = at_bf + (size_t)T * 4096;             // [4096][4096]

  hipFuncSetAttribute(reinterpret_cast<const void*>(&gemm192),
                      hipFuncAttributeMaxDynamicSharedMemorySize, 147456);
  hipFuncSetAttribute(reinterpret_cast<const void*>(&gemm256),
                      hipFuncAttributeMaxDynamicSharedMemorySize, 131072);
  hipFuncSetAttribute(reinterpret_cast<const void*>(&flash_kernel),
                      hipFuncAttributeMaxDynamicSharedMemorySize, 49152);

  cvt_bf16_kernel<<<2048, 256, 0, stream>>>(hidden, hid_bf, (long)T * HID / 4);
  cvt_bf16_kernel<<<4096, 256, 0, stream>>>(w_qkv, wreg, (long)NQKV * HID / 4);
  gemm192<<<dim3(NQKV / 192, T / 256), 512, 147456, stream>>>(hid_bf, wreg, qkv_bf, NQKV, HID);
  ln_rope_kernel<<<dim3(96, T / 16), 256, 0, stream>>>(qkv_bf, positions, qnw, qnb, knw, knb,
                                                       q_bf, k_bf, v_bf, T);
  flash_kernel<<<768, 512, 49152, stream>>>(q_bf, k_bf, v_bf, at_bf, T, w_o, wo_bf);
  gemm256<<<dim3(HID / 128, T / 256), 512, 131072, stream>>>(at_bf, wo_bf, out, HID, HID);
}